// Round 2
// baseline (130.632 us; speedup 1.0000x reference)
//
#include <hip/hip_runtime.h>

typedef _Float16 f16;
typedef f16 f16x2 __attribute__((ext_vector_type(2)));
typedef f16 f16x4 __attribute__((ext_vector_type(4)));
typedef f16 f16x8 __attribute__((ext_vector_type(8)));
typedef float f32x4 __attribute__((ext_vector_type(4)));

constexpr int Mdim = 32768, Ndim = 1024, Kdim = 1024;
constexpr int BM = 128, BN = 128, BK = 64;
constexpr int NT = Kdim / BK;   // 16 K-steps

static __device__ inline f16x2 cvt2(float a, float b) {
    return __builtin_bit_cast(f16x2, __builtin_amdgcn_cvt_pkrtz(a, b));
}

// out[b,n] = fp32(sum_k fp16(x[b,k]) * fp16(w[n,k])) + bias[n]
// (reference's early-termination mask is always-true: tstat >= 0 > TAU never holds)
__global__ __launch_bounds__(256, 2)
void etrow_gemm(const float* __restrict__ X, const float* __restrict__ W,
                const float* __restrict__ bias, float* __restrict__ out)
{
    __shared__ f16 As[2][BM * BK];   // 16 KB each buffer, XOR-swizzled rows
    __shared__ f16 Bs[2][BN * BK];

    // bijective XCD-aware swizzle (nwg = 2048, divisible by 8)
    const int bid = blockIdx.x;
    const int nwg = gridDim.x;
    const int cpx = nwg >> 3;
    const int wg  = (bid & 7) * cpx + (bid >> 3);
    const int mIdx = wg >> 3;        // Ndim/BN == 8 n-tiles, n fastest
    const int nIdx = wg & 7;

    const int tid  = threadIdx.x;
    const int lane = tid & 63;
    const int wave = tid >> 6;
    const int wr   = (wave >> 1) * 64;   // wave's row offset in tile
    const int wc   = (wave & 1) * 64;    // wave's col offset in tile

    // staging decomposition: 16 rows/pass, 8 passes; 4 floats per thread per row
    const int r0 = tid >> 4;    // 0..15
    const int c4 = tid & 15;    // which float4 within the 64-wide K slab

    const float* Xb = X + (size_t)mIdx * BM * Kdim;
    const float* Wb = W + (size_t)nIdx * BN * Kdim;

    float4 aReg[8], bReg[8];
    f32x4 acc[4][4] = {};

    auto loadTiles = [&](int kt) {
        const float* xa = Xb + kt * BK + c4 * 4;
        const float* wb = Wb + kt * BK + c4 * 4;
        #pragma unroll
        for (int p = 0; p < 8; ++p) {
            const int r = p * 16 + r0;
            aReg[p] = *(const float4*)(xa + r * Kdim);
            bReg[p] = *(const float4*)(wb + r * Kdim);
        }
    };

    auto writeTiles = [&](int buf) {
        #pragma unroll
        for (int p = 0; p < 8; ++p) {
            const int r = p * 16 + r0;
            const int byte = (r * (BK * 2) + c4 * 8) ^ ((r & 7) << 4);
            f16x2 lo = cvt2(aReg[p].x, aReg[p].y);
            f16x2 hi = cvt2(aReg[p].z, aReg[p].w);
            *(f16x4*)((char*)(&As[buf][0]) + byte) =
                __builtin_shufflevector(lo, hi, 0, 1, 2, 3);
            lo = cvt2(bReg[p].x, bReg[p].y);
            hi = cvt2(bReg[p].z, bReg[p].w);
            *(f16x4*)((char*)(&Bs[buf][0]) + byte) =
                __builtin_shufflevector(lo, hi, 0, 1, 2, 3);
        }
    };

    auto computeTile = [&](int buf) {
        #pragma unroll
        for (int s = 0; s < 2; ++s) {          // two K=32 sub-steps per BK=64
            f16x8 af[4], bf[4];
            const int kb = s * 64 + (lane >> 4) * 16;  // byte offset in row
            #pragma unroll
            for (int m = 0; m < 4; ++m) {
                const int r = wr + m * 16 + (lane & 15);
                const int byte = (r * (BK * 2) + kb) ^ ((r & 7) << 4);
                af[m] = *(const f16x8*)((const char*)(&As[buf][0]) + byte);
            }
            #pragma unroll
            for (int n = 0; n < 4; ++n) {
                const int r = wc + n * 16 + (lane & 15);
                const int byte = (r * (BK * 2) + kb) ^ ((r & 7) << 4);
                bf[n] = *(const f16x8*)((const char*)(&Bs[buf][0]) + byte);
            }
            #pragma unroll
            for (int m = 0; m < 4; ++m)
                #pragma unroll
                for (int n = 0; n < 4; ++n)
                    acc[m][n] = __builtin_amdgcn_mfma_f32_16x16x32_f16(
                        af[m], bf[n], acc[m][n], 0, 0, 0);
        }
    };

    loadTiles(0);
    writeTiles(0);
    __syncthreads();

    for (int kt = 0; kt < NT; ++kt) {
        const int cur = kt & 1;
        if (kt + 1 < NT) loadTiles(kt + 1);    // issue early: HBM hides under MFMA
        computeTile(cur);
        if (kt + 1 < NT) writeTiles(cur ^ 1);  // convert + stage next buffer
        __syncthreads();                        // one barrier per K-step
    }

    // epilogue: C/D layout col = lane&15, row = (lane>>4)*4 + reg  (m89-verified)
    const int col0  = nIdx * BN + wc + (lane & 15);
    const int rbase = mIdx * BM + wr + (lane >> 4) * 4;
    float bv[4];
    #pragma unroll
    for (int n = 0; n < 4; ++n) bv[n] = bias[col0 + n * 16];

    #pragma unroll
    for (int m = 0; m < 4; ++m) {
        #pragma unroll
        for (int j = 0; j < 4; ++j) {
            const int row = rbase + m * 16 + j;
            float* o = out + (size_t)row * Ndim + col0;
            #pragma unroll
            for (int n = 0; n < 4; ++n)
                o[n * 16] = acc[m][n][j] + bv[n];
        }
    }
}

extern "C" void kernel_launch(void* const* d_in, const int* in_sizes, int n_in,
                              void* d_out, int out_size, void* d_ws, size_t ws_size,
                              hipStream_t stream) {
    const float* X  = (const float*)d_in[0];
    const float* W  = (const float*)d_in[1];
    const float* bs = (const float*)d_in[2];
    float* out = (float*)d_out;
    const int grid = (Mdim / BM) * (Ndim / BN);   // 2048 blocks
    etrow_gemm<<<grid, 256, 0, stream>>>(X, W, bs, out);
}